// Round 5
// baseline (274.890 us; speedup 1.0000x reference)
//
#include <hip/hip_runtime.h>

// Problem constants (fixed by setup_inputs: bs=8, N=M=4096, C=128)
#define BS 8
#define NN 4096
#define MM 4096
#define CC 128
#define XT 128            // x rows per block
#define YT 128            // y rows per t-tile
#define MH 2048           // y rows per block
#define NMT (MH / YT)     // 16 y-tiles per block
#define NPH (2 * NMT)     // 32 half-K pipeline phases
#define NXT (NN / XT)     // 32 x-tiles
#define SLICE (YT * 64)   // ushorts per half-K slice (16 KB)

#define FINF_BITS 0x7F800000u

typedef __attribute__((ext_vector_type(8))) short bf16x8;
typedef __attribute__((ext_vector_type(4))) float f32x4;

// counted vmcnt wait (n = allowed outstanding VMEM ops)
#define WAITVn(n) asm volatile("s_waitcnt vmcnt(" #n ")" ::: "memory")
// rule #18: pin scheduling -- nothing may be reordered above the wait+barrier
#define SCHED_FENCE() __builtin_amdgcn_sched_barrier(0)

// RNE fp32 -> bf16 (inputs are finite normals)
__device__ inline ushort f2bf(float f) {
    unsigned u = __float_as_uint(f);
    unsigned r = (u + 0x7FFFu + ((u >> 16) & 1u)) >> 16;
    return (ushort)r;
}

// ---------------------------------------------------------------------------
// prep (y only): fp32->bf16 copy of set2 + exact fp32 y norms +
// rowmin/colmin=+inf + out=0. 8 elem/thread.
// ---------------------------------------------------------------------------
__global__ void ch_prep(const float* __restrict__ y,
                        ushort* __restrict__ y16, float* __restrict__ yn,
                        unsigned* __restrict__ rowmin, unsigned* __restrict__ colmin,
                        float* __restrict__ out) {
    int gid = blockIdx.x * blockDim.x + threadIdx.x;   // 524288 threads
    size_t i = (size_t)gid * 8;

    float4 w0 = *(const float4*)(y + i);
    float4 w1 = *(const float4*)(y + i + 4);
    ushort h[8] = {f2bf(w0.x), f2bf(w0.y), f2bf(w0.z), f2bf(w0.w),
                   f2bf(w1.x), f2bf(w1.y), f2bf(w1.z), f2bf(w1.w)};
    *(bf16x8*)(y16 + i) = *(bf16x8*)h;
    float sy = w0.x * w0.x + w0.y * w0.y + w0.z * w0.z + w0.w * w0.w +
               w1.x * w1.x + w1.y * w1.y + w1.z * w1.z + w1.w * w1.w;

#pragma unroll
    for (int mask = 1; mask <= 8; mask <<= 1)
        sy += __shfl_xor(sy, mask, 64);
    if ((threadIdx.x & 15) == 0)
        yn[gid >> 4] = sy;                 // 16 threads per 128-ch row

    if (gid < BS * NN) rowmin[gid] = FINF_BITS;
    if (gid < BS * MM) colmin[gid] = FINF_BITS;
    if (gid == 0) out[0] = 0.0f;
}

// stage one half-K slice (128 rows x 64 k = 16 KB) of y tile via
// global_load_lds width-16, dest lane-order, source chunk-swizzled c^(r&7).
// 256 threads: 1024 chunks -> 4 iterations. Counts 4 on vmcnt per wave.
__device__ __forceinline__ void stage_y(const ushort* __restrict__ Yb,
                                        ushort* __restrict__ buf,
                                        int tile, int half, int tid, int wave) {
#pragma unroll
    for (int s = 0; s < 4; ++s) {
        int f = s * 256 + tid;           // 1024 chunks = 128 rows x 8
        int r = f >> 3, cslot = f & 7;
        const ushort* g = Yb + (size_t)(tile * YT + r) * CC + half * 64 +
                          ((cslot ^ (r & 7)) * 8);
        ushort* l = buf + (size_t)(s * 256 + wave * 64) * 8;  // uniform; HW adds lane*16
        __builtin_amdgcn_global_load_lds(
            (const __attribute__((address_space(1))) void*)g,
            (__attribute__((address_space(3))) void*)l, 16, 0, 0);
    }
}

// ---------------------------------------------------------------------------
// main kernel (R20 = R19 + deferred epilogue). R19's counters showed phase
// time 3795 cyc vs pipe-max 1241 (MFMA) / ~1150 (epilogue VALU) / 768 (LDS):
// the three pipes ran SEQUENTIALLY because every wave's program order was
// read->MFMA->epilogue->barrier in lockstep. Fix: double-buffer the
// accumulator (accA/accB, +64 AGPR; unified total ~252 <= 256 at 2
// waves/SIMD) and emit tile t-1's epilogue arithmetic BETWEEN the MFMA
// clusters of tile t's h0 phase (flush shfl+atomic between h1's clusters).
// MFMA issue is non-blocking -> the epilogue VALU executes while the matrix
// pipe drains; epilogue reads prevAcc, MFMA writes curAcc: no dependency.
// Everything else (3-buffer counted-vmcnt staging per T3/T4, rule-#18
// fences at barriers only, c^(r&7) swizzles, x-in-reg af[4][4]) is
// bit-identical to R19.
// ---------------------------------------------------------------------------
__global__ __launch_bounds__(256, 2) void ch_tile(
    const float* __restrict__ Xf, const ushort* __restrict__ Y,
    const float* __restrict__ yn,
    unsigned* __restrict__ rowmin, unsigned* __restrict__ colmin) {

    __shared__ ushort pool[3 * SLICE];   // 48 KB: xs (32 KB) then 3 y slices
    __shared__ unsigned coltile[MH];     // 8 KB
    __shared__ unsigned rowtile[XT];     // 0.5 KB
    __shared__ float xnorm[XT];          // 0.5 KB
    __shared__ float ynld[MH];           // 8 KB (block's y norms)

    const int b  = blockIdx.x;           // 0..7 -> XCD pin (linear id % 8 == b)
    const int xt = blockIdx.y;           // 0..31
    const int mh = blockIdx.z;           // 0..1
    const int n0 = xt * XT;
    const int m0 = mh * MH;
    const int tid  = threadIdx.x;        // 0..255
    const int lane = tid & 63;
    const int wave = tid >> 6;           // 0..3
    const int lc   = lane & 15;          // A/B row, C col
    const int quad = lane >> 4;          // k-chunk, C row group
    const int wm = wave >> 1;            // x half (0/1)
    const int wn = wave & 1;             // y half (0/1)

    const ushort* Yb = Y + ((size_t)b * MM + m0) * CC;

    // ---- prologue A: stage x tile fp32 -> bf16 -> swizzled LDS (xs = pool);
    //      x norms; y norms -> LDS; coltile/rowtile init ----
    ushort* xs = pool;
    const float* Xb = Xf + ((size_t)b * NN + n0) * CC;
    {
        float psum[8];
#pragma unroll
        for (int s = 0; s < 8; ++s) {
            int flat = s * 256 + tid;    // 2048 chunks = 128 rows x 16
            int r = flat >> 4, c = flat & 15;
            float4 v0 = *(const float4*)(Xb + (size_t)r * CC + c * 8);
            float4 v1 = *(const float4*)(Xb + (size_t)r * CC + c * 8 + 4);
            ushort h[8] = {f2bf(v0.x), f2bf(v0.y), f2bf(v0.z), f2bf(v0.w),
                           f2bf(v1.x), f2bf(v1.y), f2bf(v1.z), f2bf(v1.w)};
            *(bf16x8*)(xs + r * CC + (c ^ (r & 7)) * 8) = *(bf16x8*)h;
            psum[s] = v0.x * v0.x + v0.y * v0.y + v0.z * v0.z + v0.w * v0.w +
                      v1.x * v1.x + v1.y * v1.y + v1.z * v1.z + v1.w * v1.w;
        }
#pragma unroll
        for (int mask = 1; mask <= 8; mask <<= 1)
#pragma unroll
            for (int s = 0; s < 8; ++s)
                psum[s] += __shfl_xor(psum[s], mask, 64);
        if ((tid & 15) == 0) {
#pragma unroll
            for (int s = 0; s < 8; ++s)
                xnorm[s * 16 + (tid >> 4)] = psum[s];
        }
    }
    {
        const float* ynb = yn + (size_t)b * MM + m0;
#pragma unroll
        for (int s = 0; s < MH / 256; ++s)
            ynld[s * 256 + tid] = ynb[s * 256 + tid];
    }
    for (int c2 = tid; c2 < MH; c2 += 256) coltile[c2] = FINF_BITS;
    if (tid < XT) rowtile[tid] = FINF_BITS;

    __syncthreads();   // xs + xnorm + ynld + coltile ready

    // ---- prologue B: hoist this wave's A operand + norms into registers ----
    bf16x8 af[4][4];   // [k-chunk32 kt][row-group i] : 64 VGPR
    const int xrow = (wm * 64 + lc) * CC;
    const int xsw  = lc & 7;
#pragma unroll
    for (int kt = 0; kt < 4; ++kt)
#pragma unroll
        for (int i = 0; i < 4; ++i)
            af[kt][i] = *(const bf16x8*)(xs + xrow + i * 16 * CC +
                                         ((kt * 4 + quad) ^ xsw) * 8);

    float xnp[4][4];
#pragma unroll
    for (int i = 0; i < 4; ++i) {
        float4 t = *(const float4*)(&xnorm[wm * 64 + i * 16 + quad * 4]);
        xnp[i][0] = t.x; xnp[i][1] = t.y; xnp[i][2] = t.z; xnp[i][3] = t.w;
    }
    float rm[4][4];
#pragma unroll
    for (int i = 0; i < 4; ++i)
#pragma unroll
        for (int r = 0; r < 4; ++r) rm[i][r] = __builtin_inff();

    __syncthreads();   // all waves done reading xs: pool may be overwritten

    // ---- prologue C: stage slices 0,1 into buffers 0,1 ----
    stage_y(Yb, pool + 0 * SLICE, 0, 0, tid, wave);
    stage_y(Yb, pool + 1 * SLICE, 0, 1, tid, wave);
    WAITVn(4);                       // slice 0 landed; slice 1 in flight
    __builtin_amdgcn_s_barrier();
    SCHED_FENCE();

    int rd = 0;                      // buffer holding the current slice
    const f32x4 z = {0.f, 0.f, 0.f, 0.f};
    f32x4 accA[4][4], accB[4][4];    // double-buffered accumulators
    float ynrA[4], ynrB[4];

    // stage slice ph+2 into the free buffer (exactly one call per phase)
    auto stage_q = [&](int ph) {
        if (ph + 2 < NPH) {
            int wr = rd + 2; if (wr >= 3) wr -= 3;
            stage_y(Yb, pool + wr * SLICE, (ph + 2) >> 1, (ph + 2) & 1,
                    tid, wave);
        }
    };
    // end-of-phase: counted wait + barrier + buffer rotate (R19 discipline)
    auto end_ph = [&](int ph) {
        SCHED_FENCE();
        if (ph + 2 < NPH) { WAITVn(4); } else { WAITVn(0); }
        __builtin_amdgcn_s_barrier();
        SCHED_FENCE();
        rd = (rd == 2) ? 0 : rd + 1;
    };

    // arithmetic half of the epilogue: d^2, rm mins, per-tile col mins
    auto epi_arith = [&](f32x4 (&pa)[4][4], float (&pyn)[4], float (&cmv)[4]) {
#pragma unroll
        for (int j = 0; j < 4; ++j) cmv[j] = __builtin_inff();
#pragma unroll
        for (int i = 0; i < 4; ++i) {
#pragma unroll
            for (int j = 0; j < 4; ++j) {
                f32x4 a = pa[i][j];
                float e0 = xnp[i][0] + fmaf(-2.0f, a[0], pyn[j]);
                float e1 = xnp[i][1] + fmaf(-2.0f, a[1], pyn[j]);
                float e2 = xnp[i][2] + fmaf(-2.0f, a[2], pyn[j]);
                float e3 = xnp[i][3] + fmaf(-2.0f, a[3], pyn[j]);
                rm[i][0] = fminf(rm[i][0], e0);
                rm[i][1] = fminf(rm[i][1], e1);
                rm[i][2] = fminf(rm[i][2], e2);
                rm[i][3] = fminf(rm[i][3], e3);
                cmv[j] = fminf(cmv[j],
                               fminf(fminf(e0, e1), fminf(e2, e3)));
            }
        }
    };
    // flush half: cross-quad reduce + LDS atomics for tile tprev
    auto epi_flush = [&](float (&cmv)[4], int tprev) {
#pragma unroll
        for (int mask = 16; mask <= 32; mask <<= 1)
#pragma unroll
            for (int j = 0; j < 4; ++j)
                cmv[j] = fminf(cmv[j], __shfl_xor(cmv[j], mask, 64));
        if (quad == 0) {
#pragma unroll
            for (int j = 0; j < 4; ++j)
                atomicMin(&coltile[tprev * YT + wn * 64 + j * 16 + lc],
                          __float_as_uint(fmaxf(cmv[j], 0.0f)));
        }
    };

    // one 128x128 tile: MFMA into cacc; epilogue of pacc interleaved between
    // the MFMA clusters (arith in h0, flush in h1). All array refs bind
    // statically at each call site (rule #20).
    auto do_tile = [&](int t, f32x4 (&cacc)[4][4], float (&cyn)[4],
                       f32x4 (&pacc)[4][4], float (&pyn)[4],
                       bool do_epi, int tprev) {
        float cmv[4];
        // ---------------- phase h0 (k-chunks 0,1) ----------------
        {
            const int ph = 2 * t;
            const ushort* ybuf = pool + rd * SLICE;
            stage_q(ph);
#pragma unroll
            for (int j = 0; j < 4; ++j)       // LDS read: no vmcnt impact
                cyn[j] = ynld[t * YT + wn * 64 + j * 16 + lc];
            {   // k-chunk 0 (acc init)
                bf16x8 yf[4];
                const int cy = ((0 + quad) ^ xsw) * 8;
#pragma unroll
                for (int j = 0; j < 4; ++j)
                    yf[j] = *(const bf16x8*)(ybuf + (wn * 64 + j * 16 + lc) * 64 + cy);
                __builtin_amdgcn_s_setprio(1);
#pragma unroll
                for (int j = 0; j < 4; ++j)
#pragma unroll
                    for (int i = 0; i < 4; ++i)
                        cacc[i][j] = __builtin_amdgcn_mfma_f32_16x16x32_bf16(
                            af[0][i], yf[j], z, 0, 0, 0);
                __builtin_amdgcn_s_setprio(0);
            }
            {   // k-chunk 1: reads, then DEFERRED EPILOGUE ARITH, then MFMA
                bf16x8 yf[4];
                const int cy = ((4 + quad) ^ xsw) * 8;
#pragma unroll
                for (int j = 0; j < 4; ++j)
                    yf[j] = *(const bf16x8*)(ybuf + (wn * 64 + j * 16 + lc) * 64 + cy);
                if (do_epi) epi_arith(pacc, pyn, cmv);   // VALU under MFMA drain
                __builtin_amdgcn_s_setprio(1);
#pragma unroll
                for (int j = 0; j < 4; ++j)
#pragma unroll
                    for (int i = 0; i < 4; ++i)
                        cacc[i][j] = __builtin_amdgcn_mfma_f32_16x16x32_bf16(
                            af[1][i], yf[j], cacc[i][j], 0, 0, 0);
                __builtin_amdgcn_s_setprio(0);
            }
            end_ph(ph);
        }
        // ---------------- phase h1 (k-chunks 2,3) ----------------
        {
            const int ph = 2 * t + 1;
            const ushort* ybuf = pool + rd * SLICE;
            stage_q(ph);
            {   // k-chunk 2
                bf16x8 yf[4];
                const int cy = ((0 + quad) ^ xsw) * 8;
#pragma unroll
                for (int j = 0; j < 4; ++j)
                    yf[j] = *(const bf16x8*)(ybuf + (wn * 64 + j * 16 + lc) * 64 + cy);
                __builtin_amdgcn_s_setprio(1);
#pragma unroll
                for (int j = 0; j < 4; ++j)
#pragma unroll
                    for (int i = 0; i < 4; ++i)
                        cacc[i][j] = __builtin_amdgcn_mfma_f32_16x16x32_bf16(
                            af[2][i], yf[j], cacc[i][j], 0, 0, 0);
                __builtin_amdgcn_s_setprio(0);
            }
            {   // k-chunk 3: reads, then DEFERRED EPILOGUE FLUSH, then MFMA
                bf16x8 yf[4];
                const int cy = ((4 + quad) ^ xsw) * 8;
#pragma unroll
                for (int j = 0; j < 4; ++j)
                    yf[j] = *(const bf16x8*)(ybuf + (wn * 64 + j * 16 + lc) * 64 + cy);
                if (do_epi) epi_flush(cmv, tprev);       // DS/shfl under MFMA drain
                __builtin_amdgcn_s_setprio(1);
#pragma unroll
                for (int j = 0; j < 4; ++j)
#pragma unroll
                    for (int i = 0; i < 4; ++i)
                        cacc[i][j] = __builtin_amdgcn_mfma_f32_16x16x32_bf16(
                            af[3][i], yf[j], cacc[i][j], 0, 0, 0);
                __builtin_amdgcn_s_setprio(0);
            }
            end_ph(ph);
        }
    };

    // tile 0 primes the pipeline (no previous epilogue)
    do_tile(0, accA, ynrA, accB, ynrB, false, 0);
#pragma unroll 1
    for (int t = 1; t + 2 < NMT; t += 2) {
        do_tile(t,     accB, ynrB, accA, ynrA, true, t - 1);
        do_tile(t + 1, accA, ynrA, accB, ynrB, true, t);
    }
    do_tile(NMT - 1, accB, ynrB, accA, ynrA, true, NMT - 2);

    // final epilogue for the last tile (serial, once)
    {
        float cmv[4];
        epi_arith(accB, ynrB, cmv);
        epi_flush(cmv, NMT - 1);
    }

    // ---- row mins: reduce across the 16 lc lanes, LDS atomic once ----
#pragma unroll
    for (int mask = 1; mask <= 8; mask <<= 1)
#pragma unroll
        for (int i = 0; i < 4; ++i)
#pragma unroll
            for (int r = 0; r < 4; ++r)
                rm[i][r] = fminf(rm[i][r], __shfl_xor(rm[i][r], mask, 64));
    if (lc == 0) {
#pragma unroll
        for (int i = 0; i < 4; ++i)
#pragma unroll
            for (int r = 0; r < 4; ++r)
                atomicMin(&rowtile[wm * 64 + i * 16 + quad * 4 + r],
                          __float_as_uint(fmaxf(rm[i][r], 0.0f)));
    }

    // ---- flush tile minima with global atomics ----
    __syncthreads();
    if (tid < XT)
        atomicMin(&rowmin[(size_t)b * NN + n0 + tid], rowtile[tid]);
    for (int c2 = tid; c2 < MH; c2 += 256)
        atomicMin(&colmin[(size_t)b * MM + m0 + c2], coltile[c2]);
}

// ---------------------------------------------------------------------------
// finalize: total = (sum w1*sqrt(rowmin) + sum w2*sqrt(colmin)) / 2
// ---------------------------------------------------------------------------
__global__ void ch_finalize(const unsigned* __restrict__ rowmin,
                            const unsigned* __restrict__ colmin,
                            const float* __restrict__ w1,
                            const float* __restrict__ w2,
                            float* __restrict__ out) {
    int i = blockIdx.x * blockDim.x + threadIdx.x;
    int stride = gridDim.x * blockDim.x;
    float s = 0.f;
    for (int idx = i; idx < BS * NN; idx += stride)
        s += w1[idx] * sqrtf(__uint_as_float(rowmin[idx])) +
             w2[idx] * sqrtf(__uint_as_float(colmin[idx]));
#pragma unroll
    for (int off = 32; off > 0; off >>= 1) s += __shfl_down(s, off, 64);
    __shared__ float ls[4];
    int lane = threadIdx.x & 63, wv = threadIdx.x >> 6;
    if (lane == 0) ls[wv] = s;
    __syncthreads();
    if (threadIdx.x == 0) {
        float t = ls[0] + ls[1] + ls[2] + ls[3];
        atomicAdd(out, 0.5f * t);
    }
}

extern "C" void kernel_launch(void* const* d_in, const int* in_sizes, int n_in,
                              void* d_out, int out_size, void* d_ws, size_t ws_size,
                              hipStream_t stream) {
    const float* set1 = (const float*)d_in[0];
    const float* set2 = (const float*)d_in[1];
    const float* w1   = (const float*)d_in[2];
    const float* w2   = (const float*)d_in[3];
    float* out = (float*)d_out;

    // workspace layout (~8.5 MiB)
    ushort*   y16    = (ushort*)d_ws;                        // BS*MM*CC bf16 (8 MB)
    float*    yn     = (float*)(y16 + (size_t)BS * MM * CC); // 128 KB
    unsigned* rowmin = (unsigned*)(yn + BS * MM);            // 128 KB (d^2 bits)
    unsigned* colmin = rowmin + BS * NN;                     // 128 KB (d^2 bits)

    ch_prep<<<BS * MM * CC / 8 / 256, 256, 0, stream>>>(
        set2, y16, yn, rowmin, colmin, out);

    dim3 grid(BS, NXT, MM / MH);   // b fastest -> linear id % 8 == b == XCD
    ch_tile<<<grid, 256, 0, stream>>>(set1, y16, yn, rowmin, colmin);

    ch_finalize<<<64, 256, 0, stream>>>(rowmin, colmin, w1, w2, out);
}

// Round 6
// 244.941 us; speedup vs baseline: 1.1223x; 1.1223x over previous
//
#include <hip/hip_runtime.h>

// Problem constants (fixed by setup_inputs: bs=8, N=M=4096, C=128)
#define BS 8
#define NN 4096
#define MM 4096
#define CC 128
#define XT 128            // x rows per block
#define YT 128            // y rows per t-tile
#define MH 2048           // y rows per block
#define NMT (MH / YT)     // 16 y-tiles per block
#define NPH (2 * NMT)     // 32 half-K pipeline phases
#define NXT (NN / XT)     // 32 x-tiles
#define SLICE (YT * 64)   // ushorts per half-K slice (16 KB)

#define FINF_BITS 0x7F800000u

typedef __attribute__((ext_vector_type(8))) short bf16x8;
typedef __attribute__((ext_vector_type(4))) float f32x4;

// counted vmcnt wait (n = allowed outstanding VMEM ops)
#define WAITVn(n) asm volatile("s_waitcnt vmcnt(" #n ")" ::: "memory")
// rule #18: pin scheduling around barriers / MFMA->epilogue order
#define SCHED_FENCE() __builtin_amdgcn_sched_barrier(0)

// RNE fp32 -> bf16 (inputs are finite normals)
__device__ inline ushort f2bf(float f) {
    unsigned u = __float_as_uint(f);
    unsigned r = (u + 0x7FFFu + ((u >> 16) & 1u)) >> 16;
    return (ushort)r;
}

// ---------------------------------------------------------------------------
// prep (y only): fp32->bf16 copy of set2 + exact fp32 y norms +
// rowmin/colmin=+inf + out=0. 8 elem/thread.
// ---------------------------------------------------------------------------
__global__ void ch_prep(const float* __restrict__ y,
                        ushort* __restrict__ y16, float* __restrict__ yn,
                        unsigned* __restrict__ rowmin, unsigned* __restrict__ colmin,
                        float* __restrict__ out) {
    int gid = blockIdx.x * blockDim.x + threadIdx.x;   // 524288 threads
    size_t i = (size_t)gid * 8;

    float4 w0 = *(const float4*)(y + i);
    float4 w1 = *(const float4*)(y + i + 4);
    ushort h[8] = {f2bf(w0.x), f2bf(w0.y), f2bf(w0.z), f2bf(w0.w),
                   f2bf(w1.x), f2bf(w1.y), f2bf(w1.z), f2bf(w1.w)};
    *(bf16x8*)(y16 + i) = *(bf16x8*)h;
    float sy = w0.x * w0.x + w0.y * w0.y + w0.z * w0.z + w0.w * w0.w +
               w1.x * w1.x + w1.y * w1.y + w1.z * w1.z + w1.w * w1.w;

#pragma unroll
    for (int mask = 1; mask <= 8; mask <<= 1)
        sy += __shfl_xor(sy, mask, 64);
    if ((threadIdx.x & 15) == 0)
        yn[gid >> 4] = sy;                 // 16 threads per 128-ch row

    if (gid < BS * NN) rowmin[gid] = FINF_BITS;
    if (gid < BS * MM) colmin[gid] = FINF_BITS;
    if (gid == 0) out[0] = 0.0f;
}

// stage one half-K slice (128 rows x 64 k = 16 KB) of y tile via
// global_load_lds width-16, dest lane-order, source chunk-swizzled c^(r&7).
// 256 threads: 1024 chunks -> 4 iterations. Counts 4 on vmcnt per wave.
__device__ __forceinline__ void stage_y(const ushort* __restrict__ Yb,
                                        ushort* __restrict__ buf,
                                        int tile, int half, int tid, int wave) {
#pragma unroll
    for (int s = 0; s < 4; ++s) {
        int f = s * 256 + tid;           // 1024 chunks = 128 rows x 8
        int r = f >> 3, cslot = f & 7;
        const ushort* g = Yb + (size_t)(tile * YT + r) * CC + half * 64 +
                          ((cslot ^ (r & 7)) * 8);
        ushort* l = buf + (size_t)(s * 256 + wave * 64) * 8;  // uniform; HW adds lane*16
        __builtin_amdgcn_global_load_lds(
            (const __attribute__((address_space(1))) void*)g,
            (__attribute__((address_space(3))) void*)l, 16, 0, 0);
    }
}

// ======== macro building blocks (NO lambdas / array-ref params: R20's
// lambda version put accA/accB on the stack -> 730 MB scratch traffic.
// All array indices compile-time; acc double-buffer via two named arrays) ====

// one k-chunk MFMA cluster: 4 yf reads + 16 MFMA. CIN0 selects C-in for the
// first chunk (z) vs accumulate. Trailing SCHED_FENCE pins the following
// epilogue part BELOW the MFMA issue (overlap: VALU under matrix-pipe drain).
#define CLUSTER(CACC, KT, S2, FIRST)                                          \
    {                                                                         \
        const int cy_ = (((S2) * 4 + quad) ^ xsw) * 8;                        \
        bf16x8 yf0_ = *(const bf16x8*)(ybuf_ + (wn * 64 +  0 + lc) * 64 + cy_);\
        bf16x8 yf1_ = *(const bf16x8*)(ybuf_ + (wn * 64 + 16 + lc) * 64 + cy_);\
        bf16x8 yf2_ = *(const bf16x8*)(ybuf_ + (wn * 64 + 32 + lc) * 64 + cy_);\
        bf16x8 yf3_ = *(const bf16x8*)(ybuf_ + (wn * 64 + 48 + lc) * 64 + cy_);\
        __builtin_amdgcn_s_setprio(1);                                        \
        _Pragma("unroll")                                                     \
        for (int i_ = 0; i_ < 4; ++i_) {                                      \
            CACC[i_][0] = __builtin_amdgcn_mfma_f32_16x16x32_bf16(            \
                af[KT][i_], yf0_, (FIRST) ? z : CACC[i_][0], 0, 0, 0);        \
            CACC[i_][1] = __builtin_amdgcn_mfma_f32_16x16x32_bf16(            \
                af[KT][i_], yf1_, (FIRST) ? z : CACC[i_][1], 0, 0, 0);        \
            CACC[i_][2] = __builtin_amdgcn_mfma_f32_16x16x32_bf16(            \
                af[KT][i_], yf2_, (FIRST) ? z : CACC[i_][2], 0, 0, 0);        \
            CACC[i_][3] = __builtin_amdgcn_mfma_f32_16x16x32_bf16(            \
                af[KT][i_], yf3_, (FIRST) ? z : CACC[i_][3], 0, 0, 0);        \
        }                                                                     \
        __builtin_amdgcn_s_setprio(0);                                        \
        SCHED_FENCE();                                                        \
    }

#define EPI_LOAD(TPREV)                                                       \
    {                                                                         \
        _Pragma("unroll")                                                     \
        for (int j_ = 0; j_ < 4; ++j_) {                                      \
            pyn[j_] = ynld[(TPREV) * YT + wn * 64 + j_ * 16 + lc];            \
            cmv[j_] = __builtin_inff();                                       \
        }                                                                     \
    }

// one i-group of the deferred epilogue. rm tracks min_j(g) with the xnp add
// deferred to the final flush (min commutes with a uniform add); the col-min
// needs xnp now -> one ds_read_b128 of xnorm (keeps xnp OUT of registers).
#define EPI_PART(PACC, I)                                                     \
    {                                                                         \
        float4 xq_ = *(const float4*)(&xnorm[wm * 64 + (I) * 16 + quad * 4]); \
        _Pragma("unroll")                                                     \
        for (int j_ = 0; j_ < 4; ++j_) {                                      \
            f32x4 a_ = PACC[I][j_];                                           \
            float g0_ = fmaf(-2.0f, a_[0], pyn[j_]);                          \
            float g1_ = fmaf(-2.0f, a_[1], pyn[j_]);                          \
            float g2_ = fmaf(-2.0f, a_[2], pyn[j_]);                          \
            float g3_ = fmaf(-2.0f, a_[3], pyn[j_]);                          \
            rm[I][0] = fminf(rm[I][0], g0_);                                  \
            rm[I][1] = fminf(rm[I][1], g1_);                                  \
            rm[I][2] = fminf(rm[I][2], g2_);                                  \
            rm[I][3] = fminf(rm[I][3], g3_);                                  \
            float m01_ = fminf(xq_.x + g0_, xq_.y + g1_);                     \
            float m23_ = fminf(xq_.z + g2_, xq_.w + g3_);                     \
            cmv[j_] = fminf(cmv[j_], fminf(m01_, m23_));                      \
        }                                                                     \
    }

#define EPI_FLUSH(TPREV)                                                      \
    {                                                                         \
        _Pragma("unroll")                                                     \
        for (int mask_ = 16; mask_ <= 32; mask_ <<= 1)                        \
            _Pragma("unroll")                                                 \
            for (int j_ = 0; j_ < 4; ++j_)                                    \
                cmv[j_] = fminf(cmv[j_], __shfl_xor(cmv[j_], mask_, 64));     \
        if (quad == 0) {                                                      \
            _Pragma("unroll")                                                 \
            for (int j_ = 0; j_ < 4; ++j_)                                    \
                atomicMin(&coltile[(TPREV) * YT + wn * 64 + j_ * 16 + lc],    \
                          __float_as_uint(fmaxf(cmv[j_], 0.0f)));             \
        }                                                                     \
    }

#define END_PH(PH)                                                            \
    {                                                                         \
        SCHED_FENCE();                                                        \
        if ((PH) + 2 < NPH) { WAITVn(4); } else { WAITVn(0); }                \
        __builtin_amdgcn_s_barrier();                                         \
        SCHED_FENCE();                                                        \
        rd = (rd == 2) ? 0 : rd + 1;                                          \
    }

#define STAGE_Q(PH)                                                           \
    if ((PH) + 2 < NPH) {                                                     \
        int wr_ = rd + 2; if (wr_ >= 3) wr_ -= 3;                             \
        stage_y(Yb, pool + wr_ * SLICE, ((PH) + 2) >> 1, ((PH) + 2) & 1,      \
                tid, wave);                                                   \
    }

// one 128x128 tile: MFMA into CACC; deferred epilogue of PACC (tile TPREV)
// interleaved one part per cluster.
#define DO_TILE(T, CACC, PACC, DOEPI, TPREV)                                  \
    {                                                                         \
        float pyn[4], cmv[4];                                                 \
        { /* phase h0 (k-chunks 0,1) */                                       \
            const int ph_ = 2 * (T);                                          \
            const ushort* ybuf_ = pool + rd * SLICE;                          \
            STAGE_Q(ph_);                                                     \
            if (DOEPI) EPI_LOAD(TPREV);                                       \
            CLUSTER(CACC, 0, 0, true);                                        \
            if (DOEPI) EPI_PART(PACC, 0);                                     \
            CLUSTER(CACC, 1, 1, false);                                       \
            if (DOEPI) EPI_PART(PACC, 1);                                     \
            END_PH(ph_);                                                      \
        }                                                                     \
        { /* phase h1 (k-chunks 2,3) */                                       \
            const int ph_ = 2 * (T) + 1;                                      \
            const ushort* ybuf_ = pool + rd * SLICE;                          \
            STAGE_Q(ph_);                                                     \
            CLUSTER(CACC, 2, 0, false);                                       \
            if (DOEPI) EPI_PART(PACC, 2);                                     \
            CLUSTER(CACC, 3, 1, false);                                       \
            if (DOEPI) EPI_PART(PACC, 3);                                     \
            if (DOEPI) EPI_FLUSH(TPREV);                                      \
            END_PH(ph_);                                                      \
        }                                                                     \
    }

// ---------------------------------------------------------------------------
// main kernel (R21 = R19 + deferred epilogue, register-safe). R19's phase
// time (3795 cyc) vs pipe-max (MFMA 620/SIMD, VALU ~700, LDS 768/CU) showed
// the pipes running sequentially: read->MFMA->epilogue->barrier in lockstep.
// R20 tested the fix via lambdas and put accA/accB on the STACK (FETCH 384MB,
// WRITE 346MB of scratch traffic). This version: straight-line macros, two
// named acc arrays (64+64 AGPR), af[4][4] (64), rm (16); xnp evicted to LDS
// (read per epilogue part), rm's xnp-add deferred to the final flush (exact).
// Tile t's 4 MFMA clusters each carry one part of tile t-1's epilogue, pinned
// below the MFMA issue by sched_barrier(0) -> VALU under matrix-pipe drain.
// Staging discipline identical to R19 (3-buffer, vmcnt(4), fences).
// ---------------------------------------------------------------------------
__global__ __launch_bounds__(256, 2) void ch_tile(
    const float* __restrict__ Xf, const ushort* __restrict__ Y,
    const float* __restrict__ yn,
    unsigned* __restrict__ rowmin, unsigned* __restrict__ colmin) {

    __shared__ ushort pool[3 * SLICE];   // 48 KB: xs (32 KB) then 3 y slices
    __shared__ unsigned coltile[MH];     // 8 KB
    __shared__ unsigned rowtile[XT];     // 0.5 KB
    __shared__ float xnorm[XT];          // 0.5 KB
    __shared__ float ynld[MH];           // 8 KB (block's y norms)

    const int b  = blockIdx.x;           // 0..7 -> XCD pin (linear id % 8 == b)
    const int xt = blockIdx.y;           // 0..31
    const int mh = blockIdx.z;           // 0..1
    const int n0 = xt * XT;
    const int m0 = mh * MH;
    const int tid  = threadIdx.x;        // 0..255
    const int lane = tid & 63;
    const int wave = tid >> 6;           // 0..3
    const int lc   = lane & 15;          // A/B row, C col
    const int quad = lane >> 4;          // k-chunk, C row group
    const int wm = wave >> 1;            // x half (0/1)
    const int wn = wave & 1;             // y half (0/1)

    const ushort* Yb = Y + ((size_t)b * MM + m0) * CC;

    // ---- prologue A: stage x tile fp32 -> bf16 -> swizzled LDS (xs = pool);
    //      x norms; y norms -> LDS; coltile/rowtile init ----
    ushort* xs = pool;
    const float* Xb = Xf + ((size_t)b * NN + n0) * CC;
    {
        float psum[8];
#pragma unroll
        for (int s = 0; s < 8; ++s) {
            int flat = s * 256 + tid;    // 2048 chunks = 128 rows x 16
            int r = flat >> 4, c = flat & 15;
            float4 v0 = *(const float4*)(Xb + (size_t)r * CC + c * 8);
            float4 v1 = *(const float4*)(Xb + (size_t)r * CC + c * 8 + 4);
            ushort h[8] = {f2bf(v0.x), f2bf(v0.y), f2bf(v0.z), f2bf(v0.w),
                           f2bf(v1.x), f2bf(v1.y), f2bf(v1.z), f2bf(v1.w)};
            *(bf16x8*)(xs + r * CC + (c ^ (r & 7)) * 8) = *(bf16x8*)h;
            psum[s] = v0.x * v0.x + v0.y * v0.y + v0.z * v0.z + v0.w * v0.w +
                      v1.x * v1.x + v1.y * v1.y + v1.z * v1.z + v1.w * v1.w;
        }
#pragma unroll
        for (int mask = 1; mask <= 8; mask <<= 1)
#pragma unroll
            for (int s = 0; s < 8; ++s)
                psum[s] += __shfl_xor(psum[s], mask, 64);
        if ((tid & 15) == 0) {
#pragma unroll
            for (int s = 0; s < 8; ++s)
                xnorm[s * 16 + (tid >> 4)] = psum[s];
        }
    }
    {
        const float* ynb = yn + (size_t)b * MM + m0;
#pragma unroll
        for (int s = 0; s < MH / 256; ++s)
            ynld[s * 256 + tid] = ynb[s * 256 + tid];
    }
    for (int c2 = tid; c2 < MH; c2 += 256) coltile[c2] = FINF_BITS;
    if (tid < XT) rowtile[tid] = FINF_BITS;

    __syncthreads();   // xs + xnorm + ynld + coltile ready

    // ---- prologue B: hoist this wave's A operand into registers ----
    bf16x8 af[4][4];   // [k-chunk32 kt][row-group i] : 64 VGPR
    const int xrow = (wm * 64 + lc) * CC;
    const int xsw  = lc & 7;
#pragma unroll
    for (int kt = 0; kt < 4; ++kt)
#pragma unroll
        for (int i = 0; i < 4; ++i)
            af[kt][i] = *(const bf16x8*)(xs + xrow + i * 16 * CC +
                                         ((kt * 4 + quad) ^ xsw) * 8);

    float rm[4][4];    // min_j of g = fmaf(-2,a,yn); xnp added at flush
#pragma unroll
    for (int i = 0; i < 4; ++i)
#pragma unroll
        for (int r = 0; r < 4; ++r) rm[i][r] = __builtin_inff();

    __syncthreads();   // all waves done reading xs: pool may be overwritten

    // ---- prologue C: stage slices 0,1 into buffers 0,1 ----
    stage_y(Yb, pool + 0 * SLICE, 0, 0, tid, wave);
    stage_y(Yb, pool + 1 * SLICE, 0, 1, tid, wave);
    WAITVn(4);                       // slice 0 landed; slice 1 in flight
    __builtin_amdgcn_s_barrier();
    SCHED_FENCE();

    int rd = 0;                      // buffer holding the current slice
    const f32x4 z = {0.f, 0.f, 0.f, 0.f};
    f32x4 accA[4][4], accB[4][4];    // double-buffered accumulators (AGPR)

    // tile 0 primes the pipeline (no previous epilogue)
    DO_TILE(0, accA, accB, 0, 0);
#pragma unroll 1
    for (int t = 1; t + 1 < NMT; t += 2) {
        DO_TILE(t,     accB, accA, 1, t - 1);
        DO_TILE(t + 1, accA, accB, 1, t);
    }
    DO_TILE(NMT - 1, accB, accA, 1, NMT - 2);

    // final epilogue for the last tile (serial, once)
    {
        float pyn[4], cmv[4];
        EPI_LOAD(NMT - 1);
        EPI_PART(accB, 0);
        EPI_PART(accB, 1);
        EPI_PART(accB, 2);
        EPI_PART(accB, 3);
        EPI_FLUSH(NMT - 1);
    }

    // ---- row mins: reduce g-mins across the 16 lc lanes, add xnp, flush ----
#pragma unroll
    for (int mask = 1; mask <= 8; mask <<= 1)
#pragma unroll
        for (int i = 0; i < 4; ++i)
#pragma unroll
            for (int r = 0; r < 4; ++r)
                rm[i][r] = fminf(rm[i][r], __shfl_xor(rm[i][r], mask, 64));
    if (lc == 0) {
#pragma unroll
        for (int i = 0; i < 4; ++i) {
            float4 xq = *(const float4*)(&xnorm[wm * 64 + i * 16 + quad * 4]);
            float xr[4] = {xq.x, xq.y, xq.z, xq.w};
#pragma unroll
            for (int r = 0; r < 4; ++r)
                atomicMin(&rowtile[wm * 64 + i * 16 + quad * 4 + r],
                          __float_as_uint(fmaxf(rm[i][r] + xr[r], 0.0f)));
        }
    }

    // ---- flush tile minima with global atomics ----
    __syncthreads();
    if (tid < XT)
        atomicMin(&rowmin[(size_t)b * NN + n0 + tid], rowtile[tid]);
    for (int c2 = tid; c2 < MH; c2 += 256)
        atomicMin(&colmin[(size_t)b * MM + m0 + c2], coltile[c2]);
}

// ---------------------------------------------------------------------------
// finalize: total = (sum w1*sqrt(rowmin) + sum w2*sqrt(colmin)) / 2
// ---------------------------------------------------------------------------
__global__ void ch_finalize(const unsigned* __restrict__ rowmin,
                            const unsigned* __restrict__ colmin,
                            const float* __restrict__ w1,
                            const float* __restrict__ w2,
                            float* __restrict__ out) {
    int i = blockIdx.x * blockDim.x + threadIdx.x;
    int stride = gridDim.x * blockDim.x;
    float s = 0.f;
    for (int idx = i; idx < BS * NN; idx += stride)
        s += w1[idx] * sqrtf(__uint_as_float(rowmin[idx])) +
             w2[idx] * sqrtf(__uint_as_float(colmin[idx]));
#pragma unroll
    for (int off = 32; off > 0; off >>= 1) s += __shfl_down(s, off, 64);
    __shared__ float ls[4];
    int lane = threadIdx.x & 63, wv = threadIdx.x >> 6;
    if (lane == 0) ls[wv] = s;
    __syncthreads();
    if (threadIdx.x == 0) {
        float t = ls[0] + ls[1] + ls[2] + ls[3];
        atomicAdd(out, 0.5f * t);
    }
}

extern "C" void kernel_launch(void* const* d_in, const int* in_sizes, int n_in,
                              void* d_out, int out_size, void* d_ws, size_t ws_size,
                              hipStream_t stream) {
    const float* set1 = (const float*)d_in[0];
    const float* set2 = (const float*)d_in[1];
    const float* w1   = (const float*)d_in[2];
    const float* w2   = (const float*)d_in[3];
    float* out = (float*)d_out;

    // workspace layout (~8.5 MiB)
    ushort*   y16    = (ushort*)d_ws;                        // BS*MM*CC bf16 (8 MB)
    float*    yn     = (float*)(y16 + (size_t)BS * MM * CC); // 128 KB
    unsigned* rowmin = (unsigned*)(yn + BS * MM);            // 128 KB (d^2 bits)
    unsigned* colmin = rowmin + BS * NN;                     // 128 KB (d^2 bits)

    ch_prep<<<BS * MM * CC / 8 / 256, 256, 0, stream>>>(
        set2, y16, yn, rowmin, colmin, out);

    dim3 grid(BS, NXT, MM / MH);   // b fastest -> linear id % 8 == b == XCD
    ch_tile<<<grid, 256, 0, stream>>>(set1, y16, yn, rowmin, colmin);

    ch_finalize<<<64, 256, 0, stream>>>(rowmin, colmin, w1, w2, out);
}

// Round 7
// 127.251 us; speedup vs baseline: 2.1602x; 1.9249x over previous
//
#include <hip/hip_runtime.h>

// Problem constants (fixed by setup_inputs: bs=8, N=M=4096, C=128)
#define BS 8
#define NN 4096
#define MM 4096
#define CC 128
#define XT 128            // x rows per block
#define YT 128            // y rows per t-tile
#define MH 1024           // y rows per block (R22: was 2048; frees LDS for 4 slices)
#define NMT (MH / YT)     // 8 y-tiles per block
#define NXT (NN / XT)     // 32 x-tiles
#define SLICE (YT * 64)   // ushorts per half-K slice (16 KB)

#define FINF_BITS 0x7F800000u

typedef __attribute__((ext_vector_type(8))) short bf16x8;
typedef __attribute__((ext_vector_type(4))) float f32x4;

// counted vmcnt wait (n = allowed outstanding VMEM ops)
#define WAITVn(n) asm volatile("s_waitcnt vmcnt(" #n ")" ::: "memory")
// rule #18: pin scheduling around barriers
#define SCHED_FENCE() __builtin_amdgcn_sched_barrier(0)

// RNE fp32 -> bf16 (inputs are finite normals)
__device__ inline ushort f2bf(float f) {
    unsigned u = __float_as_uint(f);
    unsigned r = (u + 0x7FFFu + ((u >> 16) & 1u)) >> 16;
    return (ushort)r;
}

// ---------------------------------------------------------------------------
// prep (y only): fp32->bf16 copy of set2 + exact fp32 y norms +
// rowmin/colmin=+inf + out=0. 8 elem/thread.
// ---------------------------------------------------------------------------
__global__ void ch_prep(const float* __restrict__ y,
                        ushort* __restrict__ y16, float* __restrict__ yn,
                        unsigned* __restrict__ rowmin, unsigned* __restrict__ colmin,
                        float* __restrict__ out) {
    int gid = blockIdx.x * blockDim.x + threadIdx.x;   // 524288 threads
    size_t i = (size_t)gid * 8;

    float4 w0 = *(const float4*)(y + i);
    float4 w1 = *(const float4*)(y + i + 4);
    ushort h[8] = {f2bf(w0.x), f2bf(w0.y), f2bf(w0.z), f2bf(w0.w),
                   f2bf(w1.x), f2bf(w1.y), f2bf(w1.z), f2bf(w1.w)};
    *(bf16x8*)(y16 + i) = *(bf16x8*)h;
    float sy = w0.x * w0.x + w0.y * w0.y + w0.z * w0.z + w0.w * w0.w +
               w1.x * w1.x + w1.y * w1.y + w1.z * w1.z + w1.w * w1.w;

#pragma unroll
    for (int mask = 1; mask <= 8; mask <<= 1)
        sy += __shfl_xor(sy, mask, 64);
    if ((threadIdx.x & 15) == 0)
        yn[gid >> 4] = sy;                 // 16 threads per 128-ch row

    if (gid < BS * NN) rowmin[gid] = FINF_BITS;
    if (gid < BS * MM) colmin[gid] = FINF_BITS;
    if (gid == 0) out[0] = 0.0f;
}

// stage one half-K slice (128 rows x 64 k = 16 KB) of y tile via
// global_load_lds width-16, dest lane-order, source chunk-swizzled c^(r&7).
// 256 threads: 1024 chunks -> 4 iterations. Counts 4 on vmcnt per wave.
__device__ __forceinline__ void stage_y(const ushort* __restrict__ Yb,
                                        ushort* __restrict__ buf,
                                        int tile, int half, int tid, int wave) {
#pragma unroll
    for (int s = 0; s < 4; ++s) {
        int f = s * 256 + tid;           // 1024 chunks = 128 rows x 8
        int r = f >> 3, cslot = f & 7;
        const ushort* g = Yb + (size_t)(tile * YT + r) * CC + half * 64 +
                          ((cslot ^ (r & 7)) * 8);
        ushort* l = buf + (size_t)(s * 256 + wave * 64) * 8;  // uniform; HW adds lane*16
        __builtin_amdgcn_global_load_lds(
            (const __attribute__((address_space(1))) void*)g,
            (__attribute__((address_space(3))) void*)l, 16, 0, 0);
    }
}

// ---------------------------------------------------------------------------
// main kernel (R22 = R19 regs/epilogue + super-buffer schedule). R19's
// counters: phase 3795 cyc vs pipe needs (MFMA 310 + VALU ~500 + LDS 768)
// -- ~2200 cyc/phase is barrier-period overhead (32 sync periods/block,
// 2 waves/SIMD, m233's 2-phase stall pattern). R20/R21 tried MFMA/VALU
// overlap via acc double-buffer: spilled both times (abandoned). This
// round halves the number of sync periods instead: 4x16KB slices = TWO
// 32KB super-buffers; tile t computes all K=128 from cur while tile t+1
// (8 global_load_lds) prefetches into other; ONE WAITVn(0)+s_barrier per
// TILE (prefetch issued a full tile (~3200 cyc) earlier -> drain free).
// Periods/block 32 -> 8, each 2x longer. MH 2048->1024 keeps the pool at
// 64KB -> 73 KB total LDS -> 2 blocks/CU (grid z=4, 1024 blocks, smoother
// tail). Registers/epilogue/swizzles bit-identical to R19 (VGPR ~116,
// single acc[4][4], xnp in regs -- no spill risk).
// ---------------------------------------------------------------------------
__global__ __launch_bounds__(256, 2) void ch_tile(
    const float* __restrict__ Xf, const ushort* __restrict__ Y,
    const float* __restrict__ yn,
    unsigned* __restrict__ rowmin, unsigned* __restrict__ colmin) {

    __shared__ ushort pool[4 * SLICE];   // 64 KB: xs (32 KB) aliases slices 0,1
    __shared__ unsigned coltile[MH];     // 4 KB
    __shared__ unsigned rowtile[XT];     // 0.5 KB
    __shared__ float xnorm[XT];          // 0.5 KB
    __shared__ float ynld[MH];           // 4 KB (block's y norms)

    const int b  = blockIdx.x;           // 0..7 -> XCD pin (linear id % 8 == b)
    const int xt = blockIdx.y;           // 0..31
    const int mh = blockIdx.z;           // 0..3
    const int n0 = xt * XT;
    const int m0 = mh * MH;
    const int tid  = threadIdx.x;        // 0..255
    const int lane = tid & 63;
    const int wave = tid >> 6;           // 0..3
    const int lc   = lane & 15;          // A/B row, C col
    const int quad = lane >> 4;          // k-chunk, C row group
    const int wm = wave >> 1;            // x half (0/1)
    const int wn = wave & 1;             // y half (0/1)

    const ushort* Yb = Y + ((size_t)b * MM + m0) * CC;

    // ---- prologue A: stage x tile fp32 -> bf16 -> swizzled LDS (xs = pool);
    //      x norms; y norms -> LDS; coltile/rowtile init ----
    ushort* xs = pool;
    const float* Xb = Xf + ((size_t)b * NN + n0) * CC;
    {
        float psum[8];
#pragma unroll
        for (int s = 0; s < 8; ++s) {
            int flat = s * 256 + tid;    // 2048 chunks = 128 rows x 16
            int r = flat >> 4, c = flat & 15;
            float4 v0 = *(const float4*)(Xb + (size_t)r * CC + c * 8);
            float4 v1 = *(const float4*)(Xb + (size_t)r * CC + c * 8 + 4);
            ushort h[8] = {f2bf(v0.x), f2bf(v0.y), f2bf(v0.z), f2bf(v0.w),
                           f2bf(v1.x), f2bf(v1.y), f2bf(v1.z), f2bf(v1.w)};
            *(bf16x8*)(xs + r * CC + (c ^ (r & 7)) * 8) = *(bf16x8*)h;
            psum[s] = v0.x * v0.x + v0.y * v0.y + v0.z * v0.z + v0.w * v0.w +
                      v1.x * v1.x + v1.y * v1.y + v1.z * v1.z + v1.w * v1.w;
        }
#pragma unroll
        for (int mask = 1; mask <= 8; mask <<= 1)
#pragma unroll
            for (int s = 0; s < 8; ++s)
                psum[s] += __shfl_xor(psum[s], mask, 64);
        if ((tid & 15) == 0) {
#pragma unroll
            for (int s = 0; s < 8; ++s)
                xnorm[s * 16 + (tid >> 4)] = psum[s];
        }
    }
    {
        const float* ynb = yn + (size_t)b * MM + m0;
#pragma unroll
        for (int s = 0; s < MH / 256; ++s)
            ynld[s * 256 + tid] = ynb[s * 256 + tid];
    }
    for (int c2 = tid; c2 < MH; c2 += 256) coltile[c2] = FINF_BITS;
    if (tid < XT) rowtile[tid] = FINF_BITS;

    __syncthreads();   // xs + xnorm + ynld + coltile ready

    // ---- prologue B: hoist this wave's A operand + norms into registers ----
    bf16x8 af[4][4];   // [k-chunk32 kt][row-group i] : 64 VGPR
    const int xrow = (wm * 64 + lc) * CC;
    const int xsw  = lc & 7;
#pragma unroll
    for (int kt = 0; kt < 4; ++kt)
#pragma unroll
        for (int i = 0; i < 4; ++i)
            af[kt][i] = *(const bf16x8*)(xs + xrow + i * 16 * CC +
                                         ((kt * 4 + quad) ^ xsw) * 8);

    float xnp[4][4];
#pragma unroll
    for (int i = 0; i < 4; ++i) {
        float4 t = *(const float4*)(&xnorm[wm * 64 + i * 16 + quad * 4]);
        xnp[i][0] = t.x; xnp[i][1] = t.y; xnp[i][2] = t.z; xnp[i][3] = t.w;
    }
    float rm[4][4];
#pragma unroll
    for (int i = 0; i < 4; ++i)
#pragma unroll
        for (int r = 0; r < 4; ++r) rm[i][r] = __builtin_inff();

    __syncthreads();   // all waves done reading xs: pool may be overwritten

    // ---- prologue C: stage tile 0 into super-buffer A (slices 0,1) ----
    stage_y(Yb, pool + 0 * SLICE, 0, 0, tid, wave);
    stage_y(Yb, pool + 1 * SLICE, 0, 1, tid, wave);
    WAITVn(0);                       // tile 0 fully landed
    __builtin_amdgcn_s_barrier();
    SCHED_FENCE();

    const f32x4 z = {0.f, 0.f, 0.f, 0.f};

#pragma unroll 1
    for (int t = 0; t < NMT; ++t) {
        // super-buffer select: tile parity (A = slices 0,1; B = slices 2,3)
        const ushort* ybase = pool + (t & 1) * (2 * SLICE);

        // prefetch the WHOLE next tile into the other super-buffer
        // (8 global_load_lds; lands well before next tile's barrier)
        if (t + 1 < NMT) {
            ushort* wbase = pool + ((t + 1) & 1) * (2 * SLICE);
            stage_y(Yb, wbase, t + 1, 0, tid, wave);
            stage_y(Yb, wbase + SLICE, t + 1, 1, tid, wave);
        }

        float ynr[4];
#pragma unroll
        for (int j = 0; j < 4; ++j)       // LDS read: no vmcnt impact
            ynr[j] = ynld[t * YT + wn * 64 + j * 16 + lc];

        f32x4 acc[4][4];
        // ---- 4 MFMA clusters: half-slice h, sub-chunk s2 ----
#pragma unroll
        for (int h = 0; h < 2; ++h) {
            const ushort* ybuf = ybase + h * SLICE;
#pragma unroll
            for (int s2 = 0; s2 < 2; ++s2) {
                const int ktg = h * 2 + s2;
                bf16x8 yf[4];
                const int cy = ((s2 * 4 + quad) ^ xsw) * 8;
#pragma unroll
                for (int j = 0; j < 4; ++j)
                    yf[j] = *(const bf16x8*)(ybuf + (wn * 64 + j * 16 + lc) * 64 + cy);
                __builtin_amdgcn_s_setprio(1);
#pragma unroll
                for (int j = 0; j < 4; ++j)
#pragma unroll
                    for (int i = 0; i < 4; ++i)
                        acc[i][j] = __builtin_amdgcn_mfma_f32_16x16x32_bf16(
                            af[ktg][i], yf[j], (ktg == 0) ? z : acc[i][j], 0, 0, 0);
                __builtin_amdgcn_s_setprio(0);
            }
        }

        // ---- epilogue: d^2 mins (sqrt/clamp deferred) ----
        float cmv[4];
#pragma unroll
        for (int j = 0; j < 4; ++j) cmv[j] = __builtin_inff();
#pragma unroll
        for (int i = 0; i < 4; ++i) {
#pragma unroll
            for (int j = 0; j < 4; ++j) {
                f32x4 a = acc[i][j];
                float e[4];
#pragma unroll
                for (int r = 0; r < 4; ++r)
                    e[r] = xnp[i][r] + fmaf(-2.0f, a[r], ynr[j]);
#pragma unroll
                for (int r = 0; r < 4; ++r)
                    rm[i][r] = fminf(rm[i][r], e[r]);
                cmv[j] = fminf(cmv[j],
                               fminf(fminf(e[0], e[1]), fminf(e[2], e[3])));
            }
        }
#pragma unroll
        for (int mask = 16; mask <= 32; mask <<= 1)
#pragma unroll
            for (int j = 0; j < 4; ++j)
                cmv[j] = fminf(cmv[j], __shfl_xor(cmv[j], mask, 64));
        if (quad == 0) {
#pragma unroll
            for (int j = 0; j < 4; ++j)
                atomicMin(&coltile[t * YT + wn * 64 + j * 16 + lc],
                          __float_as_uint(fmaxf(cmv[j], 0.0f)));
        }

        // ---- one sync period per tile: prefetch landed long ago ----
        SCHED_FENCE();
        WAITVn(0);
        __builtin_amdgcn_s_barrier();
        SCHED_FENCE();
    }

    // ---- row mins: reduce across the 16 lc lanes, LDS atomic once ----
#pragma unroll
    for (int mask = 1; mask <= 8; mask <<= 1)
#pragma unroll
        for (int i = 0; i < 4; ++i)
#pragma unroll
            for (int r = 0; r < 4; ++r)
                rm[i][r] = fminf(rm[i][r], __shfl_xor(rm[i][r], mask, 64));
    if (lc == 0) {
#pragma unroll
        for (int i = 0; i < 4; ++i)
#pragma unroll
            for (int r = 0; r < 4; ++r)
                atomicMin(&rowtile[wm * 64 + i * 16 + quad * 4 + r],
                          __float_as_uint(fmaxf(rm[i][r], 0.0f)));
    }

    // ---- flush tile minima with global atomics ----
    __syncthreads();
    if (tid < XT)
        atomicMin(&rowmin[(size_t)b * NN + n0 + tid], rowtile[tid]);
    for (int c2 = tid; c2 < MH; c2 += 256)
        atomicMin(&colmin[(size_t)b * MM + m0 + c2], coltile[c2]);
}

// ---------------------------------------------------------------------------
// finalize: total = (sum w1*sqrt(rowmin) + sum w2*sqrt(colmin)) / 2
// ---------------------------------------------------------------------------
__global__ void ch_finalize(const unsigned* __restrict__ rowmin,
                            const unsigned* __restrict__ colmin,
                            const float* __restrict__ w1,
                            const float* __restrict__ w2,
                            float* __restrict__ out) {
    int i = blockIdx.x * blockDim.x + threadIdx.x;
    int stride = gridDim.x * blockDim.x;
    float s = 0.f;
    for (int idx = i; idx < BS * NN; idx += stride)
        s += w1[idx] * sqrtf(__uint_as_float(rowmin[idx])) +
             w2[idx] * sqrtf(__uint_as_float(colmin[idx]));
#pragma unroll
    for (int off = 32; off > 0; off >>= 1) s += __shfl_down(s, off, 64);
    __shared__ float ls[4];
    int lane = threadIdx.x & 63, wv = threadIdx.x >> 6;
    if (lane == 0) ls[wv] = s;
    __syncthreads();
    if (threadIdx.x == 0) {
        float t = ls[0] + ls[1] + ls[2] + ls[3];
        atomicAdd(out, 0.5f * t);
    }
}

extern "C" void kernel_launch(void* const* d_in, const int* in_sizes, int n_in,
                              void* d_out, int out_size, void* d_ws, size_t ws_size,
                              hipStream_t stream) {
    const float* set1 = (const float*)d_in[0];
    const float* set2 = (const float*)d_in[1];
    const float* w1   = (const float*)d_in[2];
    const float* w2   = (const float*)d_in[3];
    float* out = (float*)d_out;

    // workspace layout (~8.5 MiB)
    ushort*   y16    = (ushort*)d_ws;                        // BS*MM*CC bf16 (8 MB)
    float*    yn     = (float*)(y16 + (size_t)BS * MM * CC); // 128 KB
    unsigned* rowmin = (unsigned*)(yn + BS * MM);            // 128 KB (d^2 bits)
    unsigned* colmin = rowmin + BS * NN;                     // 128 KB (d^2 bits)

    ch_prep<<<BS * MM * CC / 8 / 256, 256, 0, stream>>>(
        set2, y16, yn, rowmin, colmin, out);

    dim3 grid(BS, NXT, MM / MH);   // b fastest -> linear id % 8 == b == XCD
    ch_tile<<<grid, 256, 0, stream>>>(set1, y16, yn, rowmin, colmin);

    ch_finalize<<<64, 256, 0, stream>>>(rowmin, colmin, w1, w2, out);
}